// Round 4
// baseline (197.772 us; speedup 1.0000x reference)
//
#include <hip/hip_runtime.h>
#include <math.h>

// Problem constants (from reference)
#define B      512
#define DF     2048
#define DA     312
#define NTHR   320        // 5 waves; threads 0..311 each own one output column
#define RT     8          // rows per block tile in the GEMM
#define KSPLIT 16         // k-split factor (grid.y)
#define NRG    (B / RT)   // 64 row groups
#define KC     (DF / KSPLIT)

// ---------------------------------------------------------------------------
// Wave (64-lane) reduction helpers
// ---------------------------------------------------------------------------
__device__ __forceinline__ float wave_max_f(float v) {
  #pragma unroll
  for (int off = 32; off >= 1; off >>= 1)
    v = fmaxf(v, __shfl_down(v, off));
  return v;
}

__device__ __forceinline__ double wave_sum_d(double v) {
  #pragma unroll
  for (int off = 32; off >= 1; off >>= 1)
    v += __shfl_down(v, off);
  return v;
}

// Device-coherent data movement WITHOUT RMW serialization and WITHOUT fences:
// relaxed agent-scope load/store compile to ordinary coalesced
// global_load/global_store with sc0/sc1 bits (bypass local L1/L2, hit the
// device coherence point at full bandwidth). No cache-maintenance
// instructions are emitted for RELAXED ordering.
__device__ __forceinline__ void dev_store_f(float* p, float v) {
  __hip_atomic_store(p, v, __ATOMIC_RELAXED, __HIP_MEMORY_SCOPE_AGENT);
}
__device__ __forceinline__ float dev_load_f(const float* p) {
  return __hip_atomic_load(p, __ATOMIC_RELAXED, __HIP_MEMORY_SCOPE_AGENT);
}
__device__ __forceinline__ void dev_store_d(double* p, double v) {
  __hip_atomic_store(p, v, __ATOMIC_RELAXED, __HIP_MEMORY_SCOPE_AGENT);
}
__device__ __forceinline__ double dev_load_d(const double* p) {
  return __hip_atomic_load(p, __ATOMIC_RELAXED, __HIP_MEMORY_SCOPE_AGENT);
}

// ---------------------------------------------------------------------------
// Single fused kernel. Handoff ladder learned over rounds 1/3:
//   __threadfence        -> per-block full-L2 writeback walk  (~250 us)  [R1]
//   per-element RMW      -> per-lane LLC serialization        (~136 us)  [R3]
//   scoped relaxed ld/st -> coalesced BW-class through LLC    (this round)
// Phases (identical math/order to the proven 3-kernel version, absmax 0.0):
//   A (1024 blocks): split-K GEMM -> partials published via scoped stores.
//     s_waitcnt vmcnt(0) proves stores acked at the coherence point, then a
//     RELAXED atomicAdd ticket (never release: compiler would emit the
//     round-1 buffer_wbl2).
//   B (last k-block per rg): scoped-load the 16 partials (fixed order
//     p=0..15 -> deterministic), rowstats in double, scoped-store S.
//   C (last rg block): scoped-load S[512], pair reduce, write loss.
// No spin-waits -> forward-progress-safe under any scheduling.
// ---------------------------------------------------------------------------
__global__ __launch_bounds__(NTHR) void fused_kernel(
    const float* __restrict__ x_f, const float* __restrict__ W,
    const float* __restrict__ b, const int* __restrict__ labels,
    float* part, double* S, int* counters, float* out) {
  const int c    = threadIdx.x;
  const int rg   = blockIdx.x;   // row group
  const int ks   = blockIdx.y;   // k chunk
  const int row0 = rg * RT;
  const int k0   = ks * KC;

  __shared__ int       ticket_sh;
  __shared__ float     red_f[8];
  __shared__ float     bcast_max;
  __shared__ double    red_d[16];
  __shared__ long long red_i[8];
  __shared__ double    Ss[B];
  __shared__ int       Ls[B];

  // ---- Phase A: split-K GEMM partial (same math/order as proven K1) ----
  if (c < DA) {
    float acc[RT];
    #pragma unroll
    for (int r = 0; r < RT; ++r) acc[r] = 0.f;

    const float* Wp = W + (size_t)k0 * DA + c;
    const float* xp = x_f + (size_t)row0 * DF + k0;

    float wc[8];
    #pragma unroll
    for (int j = 0; j < 8; ++j) wc[j] = Wp[(size_t)j * DA];

    #pragma unroll
    for (int k = 0; k < KC; k += 8) {
      float wn[8];
      if (k + 8 < KC) {                    // prefetch next octet of W
        #pragma unroll
        for (int j = 0; j < 8; ++j) wn[j] = Wp[(size_t)(k + 8 + j) * DA];
      }
      #pragma unroll
      for (int r = 0; r < RT; ++r) {
        const float* xr = xp + (size_t)r * DF + k;  // wave-uniform -> s_load
        #pragma unroll
        for (int j = 0; j < 8; ++j) acc[r] = fmaf(xr[j], wc[j], acc[r]);
      }
      if (k + 8 < KC) {
        #pragma unroll
        for (int j = 0; j < 8; ++j) wc[j] = wn[j];
      }
    }

    // Publish partials: coalesced scoped stores (write-through to LLC).
    float* pp = part + ((size_t)(rg * KSPLIT + ks) * RT) * DA + c;
    #pragma unroll
    for (int r = 0; r < RT; ++r)
      dev_store_f(&pp[(size_t)r * DA], acc[r]);
  }

  // Drain stores to the coherence point, rendezvous, one RELAXED ticket.
  asm volatile("s_waitcnt vmcnt(0)" ::: "memory");
  __syncthreads();
  if (threadIdx.x == 0)
    ticket_sh = __hip_atomic_fetch_add(&counters[rg], 1, __ATOMIC_RELAXED,
                                       __HIP_MEMORY_SCOPE_AGENT);
  __syncthreads();
  if (ticket_sh != KSPLIT - 1) return;          // not last k-block of this rg
  asm volatile("" ::: "memory");                // don't hoist loads above ticket

  // ---- Phase B: row stats for rows row0..row0+RT-1 ----
  const int wid  = threadIdx.x >> 6;
  const int lane = threadIdx.x & 63;

  float s[RT];
  if (c < DA) {
    const float bias = b[c];
    #pragma unroll
    for (int r = 0; r < RT; ++r) {
      float ps[KSPLIT];
      #pragma unroll
      for (int p = 0; p < KSPLIT; ++p)
        ps[p] = dev_load_f(part + ((size_t)(rg * KSPLIT + p) * RT + r) * DA + c);
      float acc2 = bias;
      #pragma unroll
      for (int p = 0; p < KSPLIT; ++p) acc2 += ps[p];  // fixed order
      s[r] = acc2;
    }
  }

  for (int r = 0; r < RT; ++r) {
    float v = (c < DA) ? s[r] : -INFINITY;
    float m = wave_max_f(v);
    if (lane == 0) red_f[wid] = m;
    __syncthreads();
    if (threadIdx.x == 0) {
      float mm = red_f[0];
      #pragma unroll
      for (int w = 1; w < NTHR / 64; ++w) mm = fmaxf(mm, red_f[w]);
      bcast_max = mm;
    }
    __syncthreads();
    const float rowmax = bcast_max;

    double e  = (c < DA) ? exp((double)v - (double)rowmax) : 0.0;
    double sp = (c < DA) ? (double)v : 0.0;
    double es = wave_sum_d(e);
    double ss = wave_sum_d(sp);
    if (lane == 0) { red_d[wid] = es; red_d[8 + wid] = ss; }
    __syncthreads();
    if (threadIdx.x == 0) {
      double esum = 0.0, ssum = 0.0;
      #pragma unroll
      for (int w = 0; w < NTHR / 64; ++w) { esum += red_d[w]; ssum += red_d[8 + w]; }
      dev_store_d(&S[row0 + r],
                  ssum - (double)DA * ((double)rowmax + log(esum)));
    }
    __syncthreads();   // protect red_f/red_d reuse next round
  }

  asm volatile("s_waitcnt vmcnt(0)" ::: "memory");
  __syncthreads();
  if (threadIdx.x == 0)
    ticket_sh = __hip_atomic_fetch_add(&counters[NRG], 1, __ATOMIC_RELAXED,
                                       __HIP_MEMORY_SCOPE_AGENT);
  __syncthreads();
  if (ticket_sh != NRG - 1) return;             // not the last row-group
  asm volatile("" ::: "memory");

  // ---- Phase C: pair reduce (one block, 320 threads, exact double) ----
  for (int i = threadIdx.x; i < B; i += NTHR) {
    Ss[i] = dev_load_d(&S[i]);
    Ls[i] = labels[i];
  }
  __syncthreads();

  double lsum = 0.0;
  long long lcnt = 0;
  for (int p = threadIdx.x; p < B * B; p += NTHR) {
    int i = p >> 9;          // p / 512
    int j = p & (B - 1);     // p % 512
    if (j > i && Ls[i] == Ls[j]) { lsum += Ss[j] - Ss[i]; lcnt++; }
  }
  #pragma unroll
  for (int off = 32; off >= 1; off >>= 1) {
    lsum += __shfl_down(lsum, off);
    lcnt += __shfl_down(lcnt, off);
  }
  if (lane == 0) { red_d[wid] = lsum; red_i[wid] = lcnt; }
  __syncthreads();
  if (threadIdx.x == 0) {
    double s2 = 0.0; long long c2 = 0;
    #pragma unroll
    for (int w = 0; w < NTHR / 64; ++w) { s2 += red_d[w]; c2 += red_i[w]; }
    out[0] = (float)((c2 > 0) ? s2 / (double)c2 : s2);
  }
}

// ---------------------------------------------------------------------------
// Fallback 3-kernel path (proven, for tiny workspace): ksplit=2.
// ---------------------------------------------------------------------------
template <int KCF>
__global__ __launch_bounds__(NTHR) void gemm_partial_kernel(
    const float* __restrict__ x_f, const float* __restrict__ W,
    float* __restrict__ part) {
  const int c = threadIdx.x, rg = blockIdx.x, ks = blockIdx.y;
  const int row0 = rg * RT, k0 = ks * KCF, ksplit = DF / KCF;
  if (c >= DA) return;
  float acc[RT];
  #pragma unroll
  for (int r = 0; r < RT; ++r) acc[r] = 0.f;
  const float* Wp = W + (size_t)k0 * DA + c;
  const float* xp = x_f + (size_t)row0 * DF + k0;
  for (int k = 0; k < KCF; k += 8) {
    float w[8];
    #pragma unroll
    for (int j = 0; j < 8; ++j) w[j] = Wp[(size_t)(k + j) * DA];
    #pragma unroll
    for (int r = 0; r < RT; ++r) {
      const float* xr = xp + (size_t)r * DF + k;
      #pragma unroll
      for (int j = 0; j < 8; ++j) acc[r] = fmaf(xr[j], w[j], acc[r]);
    }
  }
  float* pp = part + ((size_t)(rg * ksplit + ks) * RT) * DA + c;
  #pragma unroll
  for (int r = 0; r < RT; ++r) pp[(size_t)r * DA] = acc[r];
}

template <int KS>
__global__ __launch_bounds__(NTHR) void row_stats_kernel(
    const float* __restrict__ part, const float* __restrict__ b,
    double* __restrict__ S) {
  __shared__ float  red_f[8];
  __shared__ double red_d[16];
  __shared__ float  bcast_max;
  const int tid = threadIdx.x, wid = tid >> 6, lane = tid & 63;
  const int row = blockIdx.x, rg = row / RT, r = row & (RT - 1);
  float v = -INFINITY;
  if (tid < DA) {
    const float* pb = part + ((size_t)(rg * KS) * RT + r) * DA + tid;
    float ps[KS];
    #pragma unroll
    for (int p = 0; p < KS; ++p) ps[p] = pb[(size_t)p * RT * DA];
    float sv = b[tid];
    #pragma unroll
    for (int p = 0; p < KS; ++p) sv += ps[p];
    v = sv;
  }
  float m = wave_max_f(v);
  if (lane == 0) red_f[wid] = m;
  __syncthreads();
  if (tid == 0) {
    float mm = red_f[0];
    #pragma unroll
    for (int w = 1; w < NTHR / 64; ++w) mm = fmaxf(mm, red_f[w]);
    bcast_max = mm;
  }
  __syncthreads();
  const float rowmax = bcast_max;
  double e  = (tid < DA) ? exp((double)v - (double)rowmax) : 0.0;
  double sp = (tid < DA) ? (double)v : 0.0;
  double es = wave_sum_d(e);
  double ss = wave_sum_d(sp);
  if (lane == 0) { red_d[wid] = es; red_d[8 + wid] = ss; }
  __syncthreads();
  if (tid == 0) {
    double esum = 0.0, ssum = 0.0;
    #pragma unroll
    for (int w = 0; w < NTHR / 64; ++w) { esum += red_d[w]; ssum += red_d[8 + w]; }
    S[row] = ssum - (double)DA * ((double)rowmax + log(esum));
  }
}

__global__ __launch_bounds__(1024) void pair_reduce_kernel(
    const double* __restrict__ S, const int* __restrict__ labels,
    float* __restrict__ out) {
  __shared__ double    Ss[B];
  __shared__ int       Ls[B];
  __shared__ double    red_d[16];
  __shared__ long long red_i[16];
  const int tid = threadIdx.x;
  if (tid < B) { Ss[tid] = S[tid]; Ls[tid] = labels[tid]; }
  __syncthreads();
  double lsum = 0.0;
  long long lcnt = 0;
  for (int p = tid; p < B * B; p += 1024) {
    int i = p >> 9, j = p & (B - 1);
    if (j > i && Ls[i] == Ls[j]) { lsum += Ss[j] - Ss[i]; lcnt++; }
  }
  #pragma unroll
  for (int off = 32; off >= 1; off >>= 1) {
    lsum += __shfl_down(lsum, off);
    lcnt += __shfl_down(lcnt, off);
  }
  const int wid = tid >> 6, lane = tid & 63;
  if (lane == 0) { red_d[wid] = lsum; red_i[wid] = lcnt; }
  __syncthreads();
  if (tid == 0) {
    double s = 0.0; long long c = 0;
    #pragma unroll
    for (int w = 0; w < 16; ++w) { s += red_d[w]; c += red_i[w]; }
    out[0] = (float)((c > 0) ? s / (double)c : s);
  }
}

// ---------------------------------------------------------------------------
extern "C" void kernel_launch(void* const* d_in, const int* in_sizes, int n_in,
                              void* d_out, int out_size, void* d_ws, size_t ws_size,
                              hipStream_t stream) {
  const float* x_f    = (const float*)d_in[0];   // [B, DF]
  const float* W      = (const float*)d_in[1];   // [DF, DA]
  const float* b      = (const float*)d_in[2];   // [DA]
  // d_in[3] = seen_att: cancels exactly for same-label pairs (unused)
  const int*   labels = (const int*)d_in[4];     // [B]

  // ws layout: [ counters: 512 B ][ S: B doubles ][ pad to 8 KB ][ part ]
  const size_t need = 8192 + (size_t)KSPLIT * B * DA * 4;
  if (ws_size >= need) {
    int*    counters = (int*)d_ws;
    double* S        = (double*)((char*)d_ws + 512);
    float*  part     = (float*)((char*)d_ws + 8192);
    hipMemsetAsync(d_ws, 0, 512, stream);        // zero tickets (ws poisoned)
    dim3 g(NRG, KSPLIT);
    fused_kernel<<<g, NTHR, 0, stream>>>(x_f, W, b, labels, part, S, counters,
                                         (float*)d_out);
  } else {                                       // tiny-ws fallback (proven)
    double* S    = (double*)d_ws;
    float*  part = (float*)((char*)d_ws + 4096);
    dim3 g1(NRG, 2);
    gemm_partial_kernel<DF / 2><<<g1, NTHR, 0, stream>>>(x_f, W, part);
    row_stats_kernel<2><<<B, NTHR, 0, stream>>>(part, b, S);
    pair_reduce_kernel<<<1, 1024, 0, stream>>>(S, labels, (float*)d_out);
  }
}

// Round 6
// 93.942 us; speedup vs baseline: 2.1053x; 2.1053x over previous
//
#include <hip/hip_runtime.h>
#include <math.h>

// Problem constants (from reference)
#define B      512
#define DF     2048
#define DA     312
#define NTHR   320        // 5 waves; threads 0..311 each own one output column
#define RT     8          // rows per block tile in the GEMM
#define KSPLIT 16         // k-split factor (grid.y)
#define NRG    (B / RT)   // 64 row groups

// ---------------------------------------------------------------------------
// Wave (64-lane) reduction helpers
// ---------------------------------------------------------------------------
__device__ __forceinline__ float wave_max_f(float v) {
  #pragma unroll
  for (int off = 32; off >= 1; off >>= 1)
    v = fmaxf(v, __shfl_down(v, off));
  return v;
}

__device__ __forceinline__ double wave_sum_d(double v) {
  #pragma unroll
  for (int off = 32; off >= 1; off >>= 1)
    v += __shfl_down(v, off);
  return v;
}

// Tiny device-coherent accessors (rounds 1/3/4 lesson: ANY intra-kernel
// cross-block mechanism costs ~6 us/MB -> use ONLY for KB-scale data).
__device__ __forceinline__ void dev_store_d(double* p, double v) {
  __hip_atomic_store(p, v, __ATOMIC_RELAXED, __HIP_MEMORY_SCOPE_AGENT);
}
__device__ __forceinline__ double dev_load_d(const double* p) {
  return __hip_atomic_load(p, __ATOMIC_RELAXED, __HIP_MEMORY_SCOPE_AGENT);
}
__device__ __forceinline__ void dev_store_i(int* p, int v) {
  __hip_atomic_store(p, v, __ATOMIC_RELAXED, __HIP_MEMORY_SCOPE_AGENT);
}
__device__ __forceinline__ int dev_load_i(const int* p) {
  return __hip_atomic_load(p, __ATOMIC_RELAXED, __HIP_MEMORY_SCOPE_AGENT);
}

// ---------------------------------------------------------------------------
// K1: split-K GEMM partials, NO LDS (proven, unchanged math). Also zeroes the
// K2' ticket with a normal store (kernel-boundary coherence, same pattern as
// the proven memset->kernel handoff). Partials cross to K2' as normal cached
// stores -- the kernel boundary provides coherence for free.
// ---------------------------------------------------------------------------
template <int KC>
__global__ __launch_bounds__(NTHR, 5) void gemm_partial_kernel(
    const float* __restrict__ x_f, const float* __restrict__ W,
    float* __restrict__ part, int* ticket) {
  const int c    = threadIdx.x;
  const int rg   = blockIdx.x;
  const int ks   = blockIdx.y;
  const int row0 = rg * RT;
  const int k0   = ks * KC;
  const int ksplit = DF / KC;

  if (blockIdx.x == 0 && blockIdx.y == 0 && threadIdx.x == 0)
    *ticket = 0;   // visible to K2' via end-of-dispatch release

  if (c >= DA) return;

  float acc[RT];
  #pragma unroll
  for (int r = 0; r < RT; ++r) acc[r] = 0.f;

  const float* Wp = W + (size_t)k0 * DA + c;
  const float* xp = x_f + (size_t)row0 * DF + k0;

  float wc[8];
  #pragma unroll
  for (int j = 0; j < 8; ++j) wc[j] = Wp[(size_t)j * DA];

  #pragma unroll
  for (int k = 0; k < KC; k += 8) {
    float wn[8];
    if (k + 8 < KC) {                    // prefetch next octet of W
      #pragma unroll
      for (int j = 0; j < 8; ++j) wn[j] = Wp[(size_t)(k + 8 + j) * DA];
    }
    #pragma unroll
    for (int r = 0; r < RT; ++r) {
      const float* xr = xp + (size_t)r * DF + k;  // wave-uniform -> s_load
      #pragma unroll
      for (int j = 0; j < 8; ++j) acc[r] = fmaf(xr[j], wc[j], acc[r]);
    }
    if (k + 8 < KC) {
      #pragma unroll
      for (int j = 0; j < 8; ++j) wc[j] = wn[j];
    }
  }

  float* pp = part + ((size_t)(rg * ksplit + ks) * RT) * DA + c;
  #pragma unroll
  for (int r = 0; r < RT; ++r) pp[(size_t)r * DA] = acc[r];
}

// ---------------------------------------------------------------------------
// K2': per-row rowstats (EXACT proven math: bias + partials p=0..KS-1, block
// max, double exp/sum, S = sum(pre) - DA*(max + log sum exp)) FUSED with the
// pair reduction via the rank identity:
//   sum_{i<j,same}(S_j - S_i) = sum_i (2*rank_i - m_i + 1) * S_i
//   count                     = sum_i rank_i
// where rank_i = #{i'<i: lbl==lbl_i}, m_i = #{lbl==lbl_i} -- computed per
// block from labels (read-only input, cached). Each block publishes ONE
// double (coef*S) + ONE int (rank) = 12 B of scoped traffic; ticket winner
// (last of 512) sums them. Tiny coherent volume -> fast (R3/R4 lesson).
// No spin-waits -> forward-progress-safe under any scheduling.
// ---------------------------------------------------------------------------
template <int KS>
__global__ __launch_bounds__(NTHR) void rowstats_pair_kernel(
    const float* __restrict__ part, const float* __restrict__ b,
    const int* __restrict__ labels,
    double* T, int* RK, int* ticket, float* __restrict__ out) {
  __shared__ float  red_f[8];
  __shared__ double red_d[16];
  __shared__ int    red_i[16];
  __shared__ float  bcast_max;
  __shared__ int    ticket_sh;
  __shared__ int    Lsh[B];

  const int tid  = threadIdx.x;
  const int wid  = tid >> 6;
  const int lane = tid & 63;
  const int row  = blockIdx.x;
  const int rg   = row / RT;
  const int r    = row & (RT - 1);

  // labels -> LDS (for rank/m scan)
  for (int i = tid; i < B; i += NTHR) Lsh[i] = labels[i];

  // issue partial loads early (independent of LDS)
  float v = -INFINITY;
  float ps[KS];
  const bool active = (tid < DA);
  if (active) {
    const float* pb = part + ((size_t)(rg * KS) * RT + r) * DA + tid;
    #pragma unroll
    for (int p = 0; p < KS; ++p) ps[p] = pb[(size_t)p * RT * DA];
  }

  __syncthreads();                      // Lsh ready

  // rank/m for this row: each thread scans a stride of labels
  const int myl = Lsh[row];
  int c_less = 0, c_all = 0;
  for (int j = tid; j < B; j += NTHR) {
    const int same = (Lsh[j] == myl) ? 1 : 0;
    c_all += same;
    if (j < row) c_less += same;
  }
  #pragma unroll
  for (int off = 32; off >= 1; off >>= 1) {
    c_less += __shfl_down(c_less, off);
    c_all  += __shfl_down(c_all,  off);
  }
  if (lane == 0) { red_i[wid] = c_less; red_i[8 + wid] = c_all; }

  // ---- rowstats (proven math, unchanged order) ----
  if (active) {
    float s = b[tid];
    #pragma unroll
    for (int p = 0; p < KS; ++p) s += ps[p];   // fixed order p=0..KS-1
    v = s;
  }

  float m = wave_max_f(v);
  if (lane == 0) red_f[wid] = m;
  __syncthreads();                      // also covers red_i before tid0 read
  if (tid == 0) {
    float mm = red_f[0];
    #pragma unroll
    for (int w = 1; w < NTHR / 64; ++w) mm = fmaxf(mm, red_f[w]);
    bcast_max = mm;
  }
  __syncthreads();
  const float rowmax = bcast_max;

  double e  = active ? exp((double)v - (double)rowmax) : 0.0;
  double sp = active ? (double)v : 0.0;
  double es = wave_sum_d(e);
  double ss = wave_sum_d(sp);
  if (lane == 0) { red_d[wid] = es; red_d[8 + wid] = ss; }
  __syncthreads();
  if (tid == 0) {
    double esum = 0.0, ssum = 0.0;
    int rank = 0, mcnt = 0;
    #pragma unroll
    for (int w = 0; w < NTHR / 64; ++w) {
      esum += red_d[w]; ssum += red_d[8 + w];
      rank += red_i[w]; mcnt += red_i[8 + w];
    }
    const double S    = ssum - (double)DA * ((double)rowmax + log(esum));
    const double coef = (double)(2 * rank - mcnt + 1);
    dev_store_d(&T[row], coef * S);     // 8 B scoped publish
    dev_store_i(&RK[row], rank);        // 4 B scoped publish
  }

  asm volatile("s_waitcnt vmcnt(0)" ::: "memory");   // publishes at LLC
  __syncthreads();
  if (tid == 0)
    ticket_sh = __hip_atomic_fetch_add(ticket, 1, __ATOMIC_RELAXED,
                                       __HIP_MEMORY_SCOPE_AGENT);
  __syncthreads();
  if (ticket_sh != B - 1) return;       // not the last row block
  asm volatile("" ::: "memory");        // don't hoist loads above ticket

  // ---- tail (winner block): sum 512 doubles + 512 ints, write loss ----
  double tloc = 0.0;
  int    rloc = 0;
  for (int i = tid; i < B; i += NTHR) { // fixed per-thread order: i, i+320
    tloc += dev_load_d(&T[i]);
    rloc += dev_load_i(&RK[i]);
  }
  #pragma unroll
  for (int off = 32; off >= 1; off >>= 1) {
    tloc += __shfl_down(tloc, off);
    rloc += __shfl_down(rloc, off);
  }
  if (lane == 0) { red_d[wid] = tloc; red_i[wid] = rloc; }
  __syncthreads();
  if (tid == 0) {
    double ts = 0.0; int rs = 0;
    #pragma unroll
    for (int w = 0; w < NTHR / 64; ++w) { ts += red_d[w]; rs += red_i[w]; }
    out[0] = (float)((rs > 0) ? ts / (double)rs : ts);
  }
}

// ---------------------------------------------------------------------------
// Fallback 3-kernel path (proven, for tiny workspace): ksplit=2.
// ---------------------------------------------------------------------------
template <int KCF>
__global__ __launch_bounds__(NTHR) void gemm_partial_fb(
    const float* __restrict__ x_f, const float* __restrict__ W,
    float* __restrict__ part) {
  const int c = threadIdx.x, rg = blockIdx.x, ks = blockIdx.y;
  const int row0 = rg * RT, k0 = ks * KCF, ksplit = DF / KCF;
  if (c >= DA) return;
  float acc[RT];
  #pragma unroll
  for (int r = 0; r < RT; ++r) acc[r] = 0.f;
  const float* Wp = W + (size_t)k0 * DA + c;
  const float* xp = x_f + (size_t)row0 * DF + k0;
  for (int k = 0; k < KCF; k += 8) {
    float w[8];
    #pragma unroll
    for (int j = 0; j < 8; ++j) w[j] = Wp[(size_t)(k + j) * DA];
    #pragma unroll
    for (int r = 0; r < RT; ++r) {
      const float* xr = xp + (size_t)r * DF + k;
      #pragma unroll
      for (int j = 0; j < 8; ++j) acc[r] = fmaf(xr[j], w[j], acc[r]);
    }
  }
  float* pp = part + ((size_t)(rg * ksplit + ks) * RT) * DA + c;
  #pragma unroll
  for (int r = 0; r < RT; ++r) pp[(size_t)r * DA] = acc[r];
}

template <int KS>
__global__ __launch_bounds__(NTHR) void row_stats_fb(
    const float* __restrict__ part, const float* __restrict__ b,
    double* __restrict__ S) {
  __shared__ float  red_f[8];
  __shared__ double red_d[16];
  __shared__ float  bcast_max;
  const int tid = threadIdx.x, wid = tid >> 6, lane = tid & 63;
  const int row = blockIdx.x, rg = row / RT, r = row & (RT - 1);
  float v = -INFINITY;
  if (tid < DA) {
    const float* pb = part + ((size_t)(rg * KS) * RT + r) * DA + tid;
    float ps[KS];
    #pragma unroll
    for (int p = 0; p < KS; ++p) ps[p] = pb[(size_t)p * RT * DA];
    float sv = b[tid];
    #pragma unroll
    for (int p = 0; p < KS; ++p) sv += ps[p];
    v = sv;
  }
  float m = wave_max_f(v);
  if (lane == 0) red_f[wid] = m;
  __syncthreads();
  if (tid == 0) {
    float mm = red_f[0];
    #pragma unroll
    for (int w = 1; w < NTHR / 64; ++w) mm = fmaxf(mm, red_f[w]);
    bcast_max = mm;
  }
  __syncthreads();
  const float rowmax = bcast_max;
  double e  = (tid < DA) ? exp((double)v - (double)rowmax) : 0.0;
  double sp = (tid < DA) ? (double)v : 0.0;
  double es = wave_sum_d(e);
  double ss = wave_sum_d(sp);
  if (lane == 0) { red_d[wid] = es; red_d[8 + wid] = ss; }
  __syncthreads();
  if (tid == 0) {
    double esum = 0.0, ssum = 0.0;
    #pragma unroll
    for (int w = 0; w < NTHR / 64; ++w) { esum += red_d[w]; ssum += red_d[8 + w]; }
    S[row] = ssum - (double)DA * ((double)rowmax + log(esum));
  }
}

__global__ __launch_bounds__(1024) void pair_reduce_fb(
    const double* __restrict__ S, const int* __restrict__ labels,
    float* __restrict__ out) {
  __shared__ double    Ss[B];
  __shared__ int       Ls[B];
  __shared__ double    red_d[16];
  __shared__ long long red_i[16];
  const int tid = threadIdx.x;
  if (tid < B) { Ss[tid] = S[tid]; Ls[tid] = labels[tid]; }
  __syncthreads();
  double lsum = 0.0;
  long long lcnt = 0;
  for (int p = tid; p < B * B; p += 1024) {
    int i = p >> 9, j = p & (B - 1);
    if (j > i && Ls[i] == Ls[j]) { lsum += Ss[j] - Ss[i]; lcnt++; }
  }
  #pragma unroll
  for (int off = 32; off >= 1; off >>= 1) {
    lsum += __shfl_down(lsum, off);
    lcnt += __shfl_down(lcnt, off);
  }
  const int wid = tid >> 6, lane = tid & 63;
  if (lane == 0) { red_d[wid] = lsum; red_i[wid] = lcnt; }
  __syncthreads();
  if (tid == 0) {
    double s = 0.0; long long c = 0;
    #pragma unroll
    for (int w = 0; w < 16; ++w) { s += red_d[w]; c += red_i[w]; }
    out[0] = (float)((c > 0) ? s / (double)c : s);
  }
}

// ---------------------------------------------------------------------------
extern "C" void kernel_launch(void* const* d_in, const int* in_sizes, int n_in,
                              void* d_out, int out_size, void* d_ws, size_t ws_size,
                              hipStream_t stream) {
  const float* x_f    = (const float*)d_in[0];   // [B, DF]
  const float* W      = (const float*)d_in[1];   // [DF, DA]
  const float* b      = (const float*)d_in[2];   // [DA]
  // d_in[3] = seen_att: cancels exactly for same-label pairs (unused)
  const int*   labels = (const int*)d_in[4];     // [B]

  // ws layout: [ticket @0][T: 512 doubles @4096][RK: 512 ints @8192]
  //            [part @16384: KSPLIT*B*DA floats]
  const size_t need = 16384 + (size_t)KSPLIT * B * DA * 4;
  if (ws_size >= need) {
    int*    ticket = (int*)d_ws;
    double* T      = (double*)((char*)d_ws + 4096);
    int*    RK     = (int*)((char*)d_ws + 8192);
    float*  part   = (float*)((char*)d_ws + 16384);
    dim3 g1(NRG, KSPLIT);
    gemm_partial_kernel<DF / KSPLIT><<<g1, NTHR, 0, stream>>>(x_f, W, part,
                                                              ticket);
    rowstats_pair_kernel<KSPLIT><<<B, NTHR, 0, stream>>>(
        part, b, labels, T, RK, ticket, (float*)d_out);
  } else {                                       // tiny-ws fallback (proven)
    double* S    = (double*)d_ws;
    float*  part = (float*)((char*)d_ws + 4096);
    dim3 g1(NRG, 2);
    gemm_partial_fb<DF / 2><<<g1, NTHR, 0, stream>>>(x_f, W, part);
    row_stats_fb<2><<<B, NTHR, 0, stream>>>(part, b, S);
    pair_reduce_fb<<<1, 1024, 0, stream>>>(S, labels, (float*)d_out);
  }
}